// Round 3
// baseline (762.199 us; speedup 1.0000x reference)
//
#include <hip/hip_runtime.h>
#include <cstdint>
#include <cstddef>

#define DIM 2048
#define NROWS 8192
#define NL 3
#define DEPTH 5
#define CF_EPS 0.01f

typedef __attribute__((ext_vector_type(8))) __bf16 bfrag;   // 8 bf16 = 4 VGPRs
typedef __attribute__((ext_vector_type(4))) float f32x4;

typedef __attribute__((address_space(1))) void gvoid;
typedef __attribute__((address_space(3))) void lvoid;

__device__ __forceinline__ void gld_lds16(const void* g, void* l) {
    // async global->LDS, 16B/lane, dest = wave-uniform base + lane*16
    __builtin_amdgcn_global_load_lds((gvoid*)g, (lvoid*)l, 16, 0, 0);
}

// Fused dual GEMM (both "NT", K-contiguous):
//   outU[m][n]  = sum_k Xh[m][k]*Uwh[n][k]                       (1 MFMA)
//   glogit      = sum_k (Xh*Gwh + Xh*Gwl + Xl*Gwh)               (3 MFMA, split-bf16)
//   gated[m][n] = sigmoid(glogit) * X[m][n]                      (epilogue)
// 128x128 tile, BK=32, 4 waves (2x2), each wave 64x64 = 4x4 MFMA tiles,
// TWO accumulator sets. Theory: K-loop is staging-latency-bound, extra MFMAs
// hide under the same global_load_lds drain that the barrier forces.
__global__ __launch_bounds__(256) void fused_mfma(
    const ushort* __restrict__ Xh, const ushort* __restrict__ Xl,
    const ushort* __restrict__ Gwh, const ushort* __restrict__ Gwl,
    const ushort* __restrict__ Uwh,
    const float* __restrict__ X,
    float* __restrict__ outU, float* __restrict__ gated)
{
    constexpr int BK = 32;
    __shared__ __align__(16) ushort sAh[128 * BK];
    __shared__ __align__(16) ushort sAl[128 * BK];
    __shared__ __align__(16) ushort sBh[128 * BK];
    __shared__ __align__(16) ushort sBl[128 * BK];
    __shared__ __align__(16) ushort sUh[128 * BK];   // 5 x 8KB = 40KB LDS

    const int tid  = threadIdx.x;
    const int wave = tid >> 6;
    const int lane = tid & 63;
    const int wm   = wave & 1;
    const int wn   = wave >> 1;
    const int m0   = blockIdx.y * 128;
    const int n0   = blockIdx.x * 128;

    // staging: wave w covers rows [w*32, w*32+32), 2 issues x 16 rows
    const size_t soff = (size_t)(wave * 32 + (lane >> 2)) * DIM + (lane & 3) * 8;
    const ushort* gAh = Xh  + (size_t)m0 * DIM + soff;
    const ushort* gAl = Xl  + (size_t)m0 * DIM + soff;
    const ushort* gBh = Gwh + (size_t)n0 * DIM + soff;
    const ushort* gBl = Gwl + (size_t)n0 * DIM + soff;
    const ushort* gUh = Uwh + (size_t)n0 * DIM + soff;

    ushort* lAh0 = &sAh[(wave * 32) * BK];  ushort* lAh1 = &sAh[(wave * 32 + 16) * BK];
    ushort* lAl0 = &sAl[(wave * 32) * BK];  ushort* lAl1 = &sAl[(wave * 32 + 16) * BK];
    ushort* lBh0 = &sBh[(wave * 32) * BK];  ushort* lBh1 = &sBh[(wave * 32 + 16) * BK];
    ushort* lBl0 = &sBl[(wave * 32) * BK];  ushort* lBl1 = &sBl[(wave * 32 + 16) * BK];
    ushort* lUh0 = &sUh[(wave * 32) * BK];  ushort* lUh1 = &sUh[(wave * 32 + 16) * BK];

    const int fm = lane & 15;     // row/col within 16-tile
    const int fq = lane >> 4;     // k-quad

    f32x4 uacc[4][4], gacc[4][4];
    #pragma unroll
    for (int i = 0; i < 4; ++i)
        #pragma unroll
        for (int j = 0; j < 4; ++j) {
            uacc[i][j] = (f32x4){0.f, 0.f, 0.f, 0.f};
            gacc[i][j] = (f32x4){0.f, 0.f, 0.f, 0.f};
        }

    for (int k0 = 0; k0 < DIM; k0 += BK) {
        __syncthreads();
        gld_lds16(gAh + k0, lAh0);  gld_lds16(gAh + (size_t)16 * DIM + k0, lAh1);
        gld_lds16(gAl + k0, lAl0);  gld_lds16(gAl + (size_t)16 * DIM + k0, lAl1);
        gld_lds16(gBh + k0, lBh0);  gld_lds16(gBh + (size_t)16 * DIM + k0, lBh1);
        gld_lds16(gBl + k0, lBl0);  gld_lds16(gBl + (size_t)16 * DIM + k0, lBl1);
        gld_lds16(gUh + k0, lUh0);  gld_lds16(gUh + (size_t)16 * DIM + k0, lUh1);
        __syncthreads();

        // hoist B-side fragments (12 frags = 48 VGPRs), stream A-side per i
        bfrag bh[4], bl[4], uh[4];
        #pragma unroll
        for (int j = 0; j < 4; ++j) {
            const int bo = (wn * 64 + j * 16 + fm) * BK + fq * 8;
            bh[j] = *(const bfrag*)&sBh[bo];
            bl[j] = *(const bfrag*)&sBl[bo];
            uh[j] = *(const bfrag*)&sUh[bo];
        }
        #pragma unroll
        for (int i = 0; i < 4; ++i) {
            const int ao = (wm * 64 + i * 16 + fm) * BK + fq * 8;
            const bfrag ah = *(const bfrag*)&sAh[ao];
            const bfrag al = *(const bfrag*)&sAl[ao];
            #pragma unroll
            for (int j = 0; j < 4; ++j) {
                uacc[i][j] = __builtin_amdgcn_mfma_f32_16x16x32_bf16(ah, uh[j], uacc[i][j], 0, 0, 0);
                gacc[i][j] = __builtin_amdgcn_mfma_f32_16x16x32_bf16(ah, bh[j], gacc[i][j], 0, 0, 0);
                gacc[i][j] = __builtin_amdgcn_mfma_f32_16x16x32_bf16(ah, bl[j], gacc[i][j], 0, 0, 0);
                gacc[i][j] = __builtin_amdgcn_mfma_f32_16x16x32_bf16(al, bh[j], gacc[i][j], 0, 0, 0);
            }
        }
    }

    // C/D layout: col = lane&15 (fm), row = fq*4 + reg
    #pragma unroll
    for (int i = 0; i < 4; ++i) {
        const int rowb = m0 + wm * 64 + i * 16 + fq * 4;
        #pragma unroll
        for (int j = 0; j < 4; ++j) {
            const int col = n0 + wn * 64 + j * 16 + fm;
            #pragma unroll
            for (int r = 0; r < 4; ++r) {
                const size_t idx = (size_t)(rowb + r) * DIM + col;
                outU[idx] = uacc[i][j][r];
                const float s = 1.0f / (1.0f + __expf(-gacc[i][j][r]));
                gated[idx] = s * X[idx];
            }
        }
    }
}

// ---------------------------------------------------------------- prep
__device__ __forceinline__ ushort f2bf_bits(float f) {
    __bf16 h = (__bf16)f;                        // RNE
    return __builtin_bit_cast(unsigned short, h);
}
__device__ __forceinline__ float bfbits2f(ushort u) {
    __bf16 h = __builtin_bit_cast(__bf16, u);
    return (float)h;
}

union U16x8 { ushort u[8]; uint4 v; };

__global__ __launch_bounds__(256) void split2(const float* __restrict__ src,
                                              ushort* __restrict__ hi,
                                              ushort* __restrict__ lo)
{
    const size_t i0 = ((size_t)blockIdx.x * 256 + threadIdx.x) * 8;
    const float4 v0 = *(const float4*)(src + i0);
    const float4 v1 = *(const float4*)(src + i0 + 4);
    const float f[8] = {v0.x, v0.y, v0.z, v0.w, v1.x, v1.y, v1.z, v1.w};
    U16x8 h, l;
    #pragma unroll
    for (int j = 0; j < 8; ++j) {
        const ushort hb = f2bf_bits(f[j]);
        h.u[j] = hb;
        l.u[j] = f2bf_bits(f[j] - bfbits2f(hb));
    }
    *(uint4*)(hi + i0) = h.v;
    *(uint4*)(lo + i0) = l.v;
}

__global__ __launch_bounds__(256) void tobf16(const float* __restrict__ src,
                                              ushort* __restrict__ dst)
{
    const size_t i0 = ((size_t)blockIdx.x * 256 + threadIdx.x) * 8;
    const float4 v0 = *(const float4*)(src + i0);
    const float4 v1 = *(const float4*)(src + i0 + 4);
    const float f[8] = {v0.x, v0.y, v0.z, v0.w, v1.x, v1.y, v1.z, v1.w};
    U16x8 h;
    #pragma unroll
    for (int j = 0; j < 8; ++j) h.u[j] = f2bf_bits(f[j]);
    *(uint4*)(dst + i0) = h.v;
}

// ---------------------------------------------------------------- epilogue
// One block per row r. Reads precomputed gated (fp32); a[l,k] = <gated, Lw[l,k]>;
// CF; Out[r,:] += z @ Vw^T  (Out already holds linear_out).
__global__ __launch_bounds__(256) void ladder_epilogue(
    const float* __restrict__ Gt,   // gated (8192,2048) fp32
    const float* __restrict__ Lw,   // (3,6,2048)
    const float* __restrict__ Vw,   // (2048,3)
    float* __restrict__ Out)
{
    const int r = blockIdx.x;
    const int tid = threadIdx.x;
    const int d0 = tid * 8;
    const float* grow = Gt + (size_t)r * DIM;

    const float4 g0 = *(const float4*)(grow + d0);
    const float4 g1 = *(const float4*)(grow + d0 + 4);
    const float gated[8] = {g0.x, g0.y, g0.z, g0.w, g1.x, g1.y, g1.z, g1.w};

    float part[NL * (DEPTH + 1)];
    #pragma unroll
    for (int lk = 0; lk < NL * (DEPTH + 1); ++lk) {
        const float* lrow = Lw + (size_t)lk * DIM + d0;
        const float4 w0 = *(const float4*)lrow;
        const float4 w1 = *(const float4*)(lrow + 4);
        part[lk] = gated[0] * w0.x + gated[1] * w0.y + gated[2] * w0.z + gated[3] * w0.w
                 + gated[4] * w1.x + gated[5] * w1.y + gated[6] * w1.z + gated[7] * w1.w;
    }

    #pragma unroll
    for (int off = 32; off > 0; off >>= 1) {
        #pragma unroll
        for (int lk = 0; lk < NL * (DEPTH + 1); ++lk)
            part[lk] += __shfl_down(part[lk], off, 64);
    }

    __shared__ float red[4][NL * (DEPTH + 1)];
    __shared__ float zsh[NL];
    const int wave = tid >> 6;
    const int lane = tid & 63;
    if (lane == 0) {
        #pragma unroll
        for (int lk = 0; lk < NL * (DEPTH + 1); ++lk) red[wave][lk] = part[lk];
    }
    __syncthreads();
    if (tid < NL) {
        float a[DEPTH + 1];
        #pragma unroll
        for (int k = 0; k < DEPTH + 1; ++k)
            a[k] = red[0][tid * 6 + k] + red[1][tid * 6 + k]
                 + red[2][tid * 6 + k] + red[3][tid * 6 + k];
        float f = 0.f;
        #pragma unroll
        for (int k = DEPTH - 1; k >= 0; --k) {
            float denom = 1.f + f;
            if (fabsf(denom) < CF_EPS) denom = (denom >= 0.f) ? CF_EPS : -CF_EPS;
            f = a[k + 1] / denom;
        }
        zsh[tid] = a[0] + f;
    }
    __syncthreads();
    const float z0 = zsh[0], z1 = zsh[1], z2 = zsh[2];

    float* orow = Out + (size_t)r * DIM + d0;
    const float4 o0 = *(const float4*)orow;
    const float4 o1 = *(const float4*)(orow + 4);
    float ov[8] = {o0.x, o0.y, o0.z, o0.w, o1.x, o1.y, o1.z, o1.w};
    #pragma unroll
    for (int j = 0; j < 8; ++j) {
        const float* vp = Vw + (size_t)(d0 + j) * NL;
        ov[j] += z0 * vp[0] + z1 * vp[1] + z2 * vp[2];
    }
    *(float4*)orow       = make_float4(ov[0], ov[1], ov[2], ov[3]);
    *(float4*)(orow + 4) = make_float4(ov[4], ov[5], ov[6], ov[7]);
}

// ---------------------------------------------------------------- launch
extern "C" void kernel_launch(void* const* d_in, const int* in_sizes, int n_in,
                              void* d_out, int out_size, void* d_ws, size_t ws_size,
                              hipStream_t stream) {
    const float* X  = (const float*)d_in[0];
    const float* Uw = (const float*)d_in[1];
    const float* Gw = (const float*)d_in[2];
    const float* Lw = (const float*)d_in[3];
    const float* Vw = (const float*)d_in[4];
    float* out = (float*)d_out;

    // ws layout (bytes) — ws_size >= 152MB proven by round-2 MFMA path running:
    //   gated fp32 @ 0           67108864
    //   Xh bf16    @ 67108864    33554432
    //   Xl bf16    @ 100663296   33554432
    //   Gwh bf16   @ 134217728    8388608
    //   Gwl bf16   @ 142606336    8388608
    //   Uwh bf16   @ 150994944    8388608
    char* ws = (char*)d_ws;
    float*  gated = (float*)ws;
    ushort* Xh  = (ushort*)(ws + 67108864);
    ushort* Xl  = (ushort*)(ws + 100663296);
    ushort* Gwh = (ushort*)(ws + 134217728);
    ushort* Gwl = (ushort*)(ws + 142606336);
    ushort* Uwh = (ushort*)(ws + 150994944);

    split2<<<dim3(8192), dim3(256), 0, stream>>>(X, Xh, Xl);
    split2<<<dim3(2048), dim3(256), 0, stream>>>(Gw, Gwh, Gwl);
    tobf16<<<dim3(2048), dim3(256), 0, stream>>>(Uw, Uwh);

    dim3 grid(DIM / 128, NROWS / 128);   // (16, 64)
    fused_mfma<<<grid, dim3(256), 0, stream>>>(Xh, Xl, Gwh, Gwl, Uwh, X, out, gated);

    ladder_epilogue<<<dim3(NROWS), dim3(256), 0, stream>>>(gated, Lw, Vw, out);
}

// Round 4
// 632.452 us; speedup vs baseline: 1.2051x; 1.2051x over previous
//
#include <hip/hip_runtime.h>
#include <cstdint>
#include <cstddef>

#define DIM 2048
#define NROWS 8192
#define NL 3
#define DEPTH 5
#define CF_EPS 0.01f

typedef __attribute__((ext_vector_type(8))) __bf16 bfrag;   // 8 bf16 = 4 VGPRs
typedef __attribute__((ext_vector_type(4))) float f32x4;

typedef __attribute__((address_space(1))) void gvoid;
typedef __attribute__((address_space(3))) void lvoid;

__device__ __forceinline__ void gld_lds16(const void* g, void* l) {
    // async global->LDS: per-lane global addr, LDS dest = wave-uniform base + lane*16
    __builtin_amdgcn_global_load_lds((gvoid*)g, (lvoid*)l, 16, 0, 0);
}

// ---------------------------------------------------------------- MFMA GEMM core
// C[m][n] = sum_k A[m][k]*B[n][k] ("NT", K-contiguous both sides).
// SPLIT: C = Ah*Bh + Ah*Bl + Al*Bh (split-bf16 ~fp32 logits).
// 128x128 tile, BK=32, 256 thr = 4 waves (2x2), wave = 64x64 = 4x4 MFMA.
//
// LDS layout (the round-4 change): per 16-row group (1 KiB), 16B chunks are
// stored [kc][r] (chunk_idx = kc*16 + r). Achieved by gather-reordering the
// global_load_lds: lane = kc*16 + r stages global (row r, k-chunk kc).
// Fragment reads then have 16B stride within a 16-lane phase -> 2-way -> free
// (was 64B stride -> 8-way conflict, SQ_LDS_BANK_CONFLICT 1.7e7).
template<bool SPLIT>
__device__ __forceinline__ void gemm_core(
    const ushort* __restrict__ Ah, const ushort* __restrict__ Al,
    const ushort* __restrict__ Bh, const ushort* __restrict__ Bl,
    float* __restrict__ C)
{
    constexpr int BK = 32;
    __shared__ __align__(16) ushort sAh[128 * BK];
    __shared__ __align__(16) ushort sBh[128 * BK];
    __shared__ __align__(16) ushort sAl[SPLIT ? 128 * BK : 8];
    __shared__ __align__(16) ushort sBl[SPLIT ? 128 * BK : 8];

    const int tid  = threadIdx.x;
    const int wave = tid >> 6;
    const int lane = tid & 63;
    const int wm   = wave & 1;
    const int wn   = wave >> 1;
    const int m0   = blockIdx.y * 128;
    const int n0   = blockIdx.x * 128;

    // gather-reordered staging: lane -> (r = lane&15, kc = lane>>4)
    const int sr = lane & 15;
    const int skc = lane >> 4;
    // wave w stages groups {2w, 2w+1} (rows [w*32, w*32+32)) of each tile
    const size_t lgo = (size_t)sr * DIM + skc * 8;            // per-lane offset
    const ushort* gAh0 = Ah + (size_t)(m0 + wave * 32) * DIM + lgo;
    const ushort* gAh1 = gAh0 + (size_t)16 * DIM;
    const ushort* gBh0 = Bh + (size_t)(n0 + wave * 32) * DIM + lgo;
    const ushort* gBh1 = gBh0 + (size_t)16 * DIM;
    const ushort* gAl0 = SPLIT ? Al + (size_t)(m0 + wave * 32) * DIM + lgo : nullptr;
    const ushort* gAl1 = SPLIT ? gAl0 + (size_t)16 * DIM : nullptr;
    const ushort* gBl0 = SPLIT ? Bl + (size_t)(n0 + wave * 32) * DIM + lgo : nullptr;
    const ushort* gBl1 = SPLIT ? gBl0 + (size_t)16 * DIM : nullptr;

    // LDS dest bases (ushort units): group g at g*512; wave's groups 2w, 2w+1
    ushort* lAh0 = &sAh[wave * 1024];  ushort* lAh1 = &sAh[wave * 1024 + 512];
    ushort* lBh0 = &sBh[wave * 1024];  ushort* lBh1 = &sBh[wave * 1024 + 512];
    ushort* lAl0 = &sAl[SPLIT ? wave * 1024 : 0];
    ushort* lAl1 = &sAl[SPLIT ? wave * 1024 + 512 : 0];
    ushort* lBl0 = &sBl[SPLIT ? wave * 1024 : 0];
    ushort* lBl1 = &sBl[SPLIT ? wave * 1024 + 512 : 0];

    const int fm = lane & 15;     // row/col within 16-tile
    const int fq = lane >> 4;     // k-quad

    f32x4 acc[4][4];
    #pragma unroll
    for (int i = 0; i < 4; ++i)
        #pragma unroll
        for (int j = 0; j < 4; ++j)
            acc[i][j] = (f32x4){0.f, 0.f, 0.f, 0.f};

    for (int k0 = 0; k0 < DIM; k0 += BK) {
        __syncthreads();
        gld_lds16(gAh0 + k0, lAh0);  gld_lds16(gAh1 + k0, lAh1);
        gld_lds16(gBh0 + k0, lBh0);  gld_lds16(gBh1 + k0, lBh1);
        if constexpr (SPLIT) {
            gld_lds16(gAl0 + k0, lAl0);  gld_lds16(gAl1 + k0, lAl1);
            gld_lds16(gBl0 + k0, lBl0);  gld_lds16(gBl1 + k0, lBl1);
        }
        __syncthreads();

        // fragment at tile-row R = base16 + fm, k-quad fq:
        //   ushort offset = (R>>4)*512 + fq*128 + fm*8
        bfrag bh[4], bl[4];
        #pragma unroll
        for (int j = 0; j < 4; ++j) {
            const int bo = (wn * 4 + j) * 512 + fq * 128 + fm * 8;
            bh[j] = *(const bfrag*)&sBh[bo];
            if constexpr (SPLIT) bl[j] = *(const bfrag*)&sBl[bo];
        }
        #pragma unroll
        for (int i = 0; i < 4; ++i) {
            const int ao = (wm * 4 + i) * 512 + fq * 128 + fm * 8;
            const bfrag ah = *(const bfrag*)&sAh[ao];
            bfrag al;
            if constexpr (SPLIT) al = *(const bfrag*)&sAl[ao];
            #pragma unroll
            for (int j = 0; j < 4; ++j) {
                acc[i][j] = __builtin_amdgcn_mfma_f32_16x16x32_bf16(ah, bh[j], acc[i][j], 0, 0, 0);
                if constexpr (SPLIT) {
                    acc[i][j] = __builtin_amdgcn_mfma_f32_16x16x32_bf16(ah, bl[j], acc[i][j], 0, 0, 0);
                    acc[i][j] = __builtin_amdgcn_mfma_f32_16x16x32_bf16(al, bh[j], acc[i][j], 0, 0, 0);
                }
            }
        }
    }

    // C/D layout: col = lane&15 (fm), row = fq*4 + reg
    #pragma unroll
    for (int i = 0; i < 4; ++i) {
        const int rowb = m0 + wm * 64 + i * 16 + fq * 4;
        #pragma unroll
        for (int j = 0; j < 4; ++j) {
            const int col = n0 + wn * 64 + j * 16 + fm;
            #pragma unroll
            for (int r = 0; r < 4; ++r)
                C[(size_t)(rowb + r) * DIM + col] = acc[i][j][r];
        }
    }
}

// distinct kernel names for profiler attribution (round-2 conflated them)
__global__ __launch_bounds__(256) void u_gemm(
    const ushort* __restrict__ Ah, const ushort* __restrict__ Bh,
    float* __restrict__ C)
{
    gemm_core<false>(Ah, nullptr, Bh, nullptr, C);
}

__global__ __launch_bounds__(256) void gate_gemm(
    const ushort* __restrict__ Ah, const ushort* __restrict__ Al,
    const ushort* __restrict__ Bh, const ushort* __restrict__ Bl,
    float* __restrict__ C)
{
    gemm_core<true>(Ah, Al, Bh, Bl, C);
}

// ---------------------------------------------------------------- prep
__device__ __forceinline__ ushort f2bf_bits(float f) {
    __bf16 h = (__bf16)f;                        // RNE
    return __builtin_bit_cast(unsigned short, h);
}
__device__ __forceinline__ float bfbits2f(ushort u) {
    __bf16 h = __builtin_bit_cast(__bf16, u);
    return (float)h;
}

union U16x8 { ushort u[8]; uint4 v; };

__global__ __launch_bounds__(256) void split2(const float* __restrict__ src,
                                              ushort* __restrict__ hi,
                                              ushort* __restrict__ lo)
{
    const size_t i0 = ((size_t)blockIdx.x * 256 + threadIdx.x) * 8;
    const float4 v0 = *(const float4*)(src + i0);
    const float4 v1 = *(const float4*)(src + i0 + 4);
    const float f[8] = {v0.x, v0.y, v0.z, v0.w, v1.x, v1.y, v1.z, v1.w};
    U16x8 h, l;
    #pragma unroll
    for (int j = 0; j < 8; ++j) {
        const ushort hb = f2bf_bits(f[j]);
        h.u[j] = hb;
        l.u[j] = f2bf_bits(f[j] - bfbits2f(hb));
    }
    *(uint4*)(hi + i0) = h.v;
    *(uint4*)(lo + i0) = l.v;
}

__global__ __launch_bounds__(256) void tobf16(const float* __restrict__ src,
                                              ushort* __restrict__ dst)
{
    const size_t i0 = ((size_t)blockIdx.x * 256 + threadIdx.x) * 8;
    const float4 v0 = *(const float4*)(src + i0);
    const float4 v1 = *(const float4*)(src + i0 + 4);
    const float f[8] = {v0.x, v0.y, v0.z, v0.w, v1.x, v1.y, v1.z, v1.w};
    U16x8 h;
    #pragma unroll
    for (int j = 0; j < 8; ++j) h.u[j] = f2bf_bits(f[j]);
    *(uint4*)(dst + i0) = h.v;
}

// ---------------------------------------------------------------- epilogue (round-2, proven)
__global__ __launch_bounds__(256) void ladder_epilogue(
    const float* __restrict__ X,
    const float* __restrict__ G,    // gate logits fp32
    const float* __restrict__ Lw,   // (3,6,2048)
    const float* __restrict__ Vw,   // (2048,3)
    float* __restrict__ Out)
{
    const int r = blockIdx.x;
    const int tid = threadIdx.x;
    const int d0 = tid * 8;
    const float* xrow = X + (size_t)r * DIM;
    const float* grow = G + (size_t)r * DIM;

    const float4 xv0 = *(const float4*)(xrow + d0);
    const float4 xv1 = *(const float4*)(xrow + d0 + 4);
    const float4 gv0 = *(const float4*)(grow + d0);
    const float4 gv1 = *(const float4*)(grow + d0 + 4);

    float gated[8];
    {
        const float gx[8] = {gv0.x, gv0.y, gv0.z, gv0.w, gv1.x, gv1.y, gv1.z, gv1.w};
        const float xx[8] = {xv0.x, xv0.y, xv0.z, xv0.w, xv1.x, xv1.y, xv1.z, xv1.w};
        #pragma unroll
        for (int j = 0; j < 8; ++j) {
            const float s = 1.0f / (1.0f + __expf(-gx[j]));
            gated[j] = s * xx[j];
        }
    }

    float part[NL * (DEPTH + 1)];
    #pragma unroll
    for (int lk = 0; lk < NL * (DEPTH + 1); ++lk) {
        const float* lrow = Lw + (size_t)lk * DIM + d0;
        const float4 w0 = *(const float4*)lrow;
        const float4 w1 = *(const float4*)(lrow + 4);
        part[lk] = gated[0] * w0.x + gated[1] * w0.y + gated[2] * w0.z + gated[3] * w0.w
                 + gated[4] * w1.x + gated[5] * w1.y + gated[6] * w1.z + gated[7] * w1.w;
    }

    #pragma unroll
    for (int off = 32; off > 0; off >>= 1) {
        #pragma unroll
        for (int lk = 0; lk < NL * (DEPTH + 1); ++lk)
            part[lk] += __shfl_down(part[lk], off, 64);
    }

    __shared__ float red[4][NL * (DEPTH + 1)];
    __shared__ float zsh[NL];
    const int wave = tid >> 6;
    const int lane = tid & 63;
    if (lane == 0) {
        #pragma unroll
        for (int lk = 0; lk < NL * (DEPTH + 1); ++lk) red[wave][lk] = part[lk];
    }
    __syncthreads();
    if (tid < NL) {
        float a[DEPTH + 1];
        #pragma unroll
        for (int k = 0; k < DEPTH + 1; ++k)
            a[k] = red[0][tid * 6 + k] + red[1][tid * 6 + k]
                 + red[2][tid * 6 + k] + red[3][tid * 6 + k];
        float f = 0.f;
        #pragma unroll
        for (int k = DEPTH - 1; k >= 0; --k) {
            float denom = 1.f + f;
            if (fabsf(denom) < CF_EPS) denom = (denom >= 0.f) ? CF_EPS : -CF_EPS;
            f = a[k + 1] / denom;
        }
        zsh[tid] = a[0] + f;
    }
    __syncthreads();
    const float z0 = zsh[0], z1 = zsh[1], z2 = zsh[2];

    float* orow = Out + (size_t)r * DIM + d0;
    const float4 o0 = *(const float4*)orow;
    const float4 o1 = *(const float4*)(orow + 4);
    float ov[8] = {o0.x, o0.y, o0.z, o0.w, o1.x, o1.y, o1.z, o1.w};
    #pragma unroll
    for (int j = 0; j < 8; ++j) {
        const float* vp = Vw + (size_t)(d0 + j) * NL;
        ov[j] += z0 * vp[0] + z1 * vp[1] + z2 * vp[2];
    }
    *(float4*)orow       = make_float4(ov[0], ov[1], ov[2], ov[3]);
    *(float4*)(orow + 4) = make_float4(ov[4], ov[5], ov[6], ov[7]);
}

// ---------------------------------------------------------------- launch
extern "C" void kernel_launch(void* const* d_in, const int* in_sizes, int n_in,
                              void* d_out, int out_size, void* d_ws, size_t ws_size,
                              hipStream_t stream) {
    const float* X  = (const float*)d_in[0];
    const float* Uw = (const float*)d_in[1];
    const float* Gw = (const float*)d_in[2];
    const float* Lw = (const float*)d_in[3];
    const float* Vw = (const float*)d_in[4];
    float* out = (float*)d_out;

    // ws layout (bytes):
    //   gbuf fp32  @ 0           67108864   (gate logits)
    //   Xh bf16    @ 67108864    33554432
    //   Xl bf16    @ 100663296   33554432
    //   Gwh bf16   @ 134217728    8388608
    //   Gwl bf16   @ 142606336    8388608
    //   Uwh bf16   @ 150994944    8388608
    char* ws = (char*)d_ws;
    float*  gbuf = (float*)ws;
    ushort* Xh  = (ushort*)(ws + 67108864);
    ushort* Xl  = (ushort*)(ws + 100663296);
    ushort* Gwh = (ushort*)(ws + 134217728);
    ushort* Gwl = (ushort*)(ws + 142606336);
    ushort* Uwh = (ushort*)(ws + 150994944);

    split2<<<dim3(8192), dim3(256), 0, stream>>>(X, Xh, Xl);
    split2<<<dim3(2048), dim3(256), 0, stream>>>(Gw, Gwh, Gwl);
    tobf16<<<dim3(2048), dim3(256), 0, stream>>>(Uw, Uwh);

    dim3 grid(DIM / 128, NROWS / 128);   // (16, 64)
    u_gemm   <<<grid, dim3(256), 0, stream>>>(Xh, Uwh, out);
    gate_gemm<<<grid, dim3(256), 0, stream>>>(Xh, Xl, Gwh, Gwl, gbuf);

    ladder_epilogue<<<dim3(NROWS), dim3(256), 0, stream>>>(X, gbuf, Lw, Vw, out);
}

// Round 5
// 605.481 us; speedup vs baseline: 1.2588x; 1.0445x over previous
//
#include <hip/hip_runtime.h>
#include <cstdint>
#include <cstddef>

#define DIM 2048
#define NROWS 8192
#define NL 3
#define DEPTH 5
#define CF_EPS 0.01f

typedef __attribute__((ext_vector_type(8))) __bf16 bfrag;   // 8 bf16 = 4 VGPRs
typedef __attribute__((ext_vector_type(4))) float f32x4;

typedef __attribute__((address_space(1))) void gvoid;
typedef __attribute__((address_space(3))) void lvoid;

__device__ __forceinline__ void gld_lds16(const void* g, void* l) {
    // async global->LDS: 16B/lane, monotone lane->addr (coalescing-critical:
    // round-4 A/B showed gather-reorder costs 20% even though it zeroes LDS
    // bank conflicts — conflicts here are benign, keep this layout).
    __builtin_amdgcn_global_load_lds((gvoid*)g, (lvoid*)l, 16, 0, 0);
}

// ---------------------------------------------------------------- merged dual GEMM
// One dispatch, 2048 blocks. Per block (block-uniform branch):
//   isGate: C = Xh*Gwh + Xh*Gwl + Xl*Gwh  -> gbuf   (split-bf16, 48 MFMA/step)
//   else  : C = Xh*Uwh                    -> outU   (16 MFMA/step)
// Theory: both are staging-drain-bound; mixing heavy (gate) and light (U)
// blocks on a CU lets U's drains hide under gate's MFMA bursts instead of
// running as a separate serialized drain-bound dispatch.
// 128x128 tile, BK=32, 4 waves (2x2), wave = 64x64 = 4x4 MFMA tiles.
__global__ __launch_bounds__(256) void dual_gemm(
    const ushort* __restrict__ Xh, const ushort* __restrict__ Xl,
    const ushort* __restrict__ Gwh, const ushort* __restrict__ Gwl,
    const ushort* __restrict__ Uwh,
    float* __restrict__ outU, float* __restrict__ gbuf)
{
    constexpr int BK = 32;
    __shared__ __align__(16) ushort sAh[128 * BK];
    __shared__ __align__(16) ushort sBh[128 * BK];
    __shared__ __align__(16) ushort sAl[128 * BK];
    __shared__ __align__(16) ushort sBl[128 * BK];

    const int tid  = threadIdx.x;
    const int wave = tid >> 6;
    const int lane = tid & 63;
    const int wm   = wave & 1;
    const int wn   = wave >> 1;

    // bx in [0,32): n-tile = bx>>1; isGate mixes across CUs/XCDs via (bx+by)&1
    const bool isGate = ((blockIdx.x + blockIdx.y) & 1) != 0;
    const int n0 = (blockIdx.x >> 1) * 128;
    const int m0 = blockIdx.y * 128;

    const ushort* Bh = isGate ? Gwh : Uwh;
    float* C = isGate ? gbuf : outU;

    // monotone staging (round-2 proven): wave w rows [w*32,w*32+32), 2 issues;
    // lane -> row = lane>>2, 16B chunk = lane&3
    const size_t soff = (size_t)(wave * 32 + (lane >> 2)) * DIM + (lane & 3) * 8;
    const ushort* gAh = Xh + (size_t)m0 * DIM + soff;
    const ushort* gBh = Bh + (size_t)n0 * DIM + soff;
    const ushort* gAl = Xl  + (size_t)m0 * DIM + soff;
    const ushort* gBl = Gwl + (size_t)n0 * DIM + soff;

    ushort* lAh0 = &sAh[(wave * 32) * BK];  ushort* lAh1 = &sAh[(wave * 32 + 16) * BK];
    ushort* lBh0 = &sBh[(wave * 32) * BK];  ushort* lBh1 = &sBh[(wave * 32 + 16) * BK];
    ushort* lAl0 = &sAl[(wave * 32) * BK];  ushort* lAl1 = &sAl[(wave * 32 + 16) * BK];
    ushort* lBl0 = &sBl[(wave * 32) * BK];  ushort* lBl1 = &sBl[(wave * 32 + 16) * BK];

    const int fm = lane & 15;     // row/col within 16-tile
    const int fq = lane >> 4;     // k-quad

    f32x4 acc[4][4];
    #pragma unroll
    for (int i = 0; i < 4; ++i)
        #pragma unroll
        for (int j = 0; j < 4; ++j)
            acc[i][j] = (f32x4){0.f, 0.f, 0.f, 0.f};

    for (int k0 = 0; k0 < DIM; k0 += BK) {
        __syncthreads();
        gld_lds16(gAh + k0, lAh0);  gld_lds16(gAh + (size_t)16 * DIM + k0, lAh1);
        gld_lds16(gBh + k0, lBh0);  gld_lds16(gBh + (size_t)16 * DIM + k0, lBh1);
        if (isGate) {
            gld_lds16(gAl + k0, lAl0);  gld_lds16(gAl + (size_t)16 * DIM + k0, lAl1);
            gld_lds16(gBl + k0, lBl0);  gld_lds16(gBl + (size_t)16 * DIM + k0, lBl1);
        }
        __syncthreads();

        bfrag bh[4], bl[4];
        #pragma unroll
        for (int j = 0; j < 4; ++j) {
            const int bo = (wn * 64 + j * 16 + fm) * BK + fq * 8;
            bh[j] = *(const bfrag*)&sBh[bo];
            bl[j] = *(const bfrag*)&sBl[bo];
        }
        if (isGate) {
            #pragma unroll
            for (int i = 0; i < 4; ++i) {
                const int ao = (wm * 64 + i * 16 + fm) * BK + fq * 8;
                const bfrag ah = *(const bfrag*)&sAh[ao];
                const bfrag al = *(const bfrag*)&sAl[ao];
                #pragma unroll
                for (int j = 0; j < 4; ++j) {
                    acc[i][j] = __builtin_amdgcn_mfma_f32_16x16x32_bf16(ah, bh[j], acc[i][j], 0, 0, 0);
                    acc[i][j] = __builtin_amdgcn_mfma_f32_16x16x32_bf16(ah, bl[j], acc[i][j], 0, 0, 0);
                    acc[i][j] = __builtin_amdgcn_mfma_f32_16x16x32_bf16(al, bh[j], acc[i][j], 0, 0, 0);
                }
            }
        } else {
            #pragma unroll
            for (int i = 0; i < 4; ++i) {
                const int ao = (wm * 64 + i * 16 + fm) * BK + fq * 8;
                const bfrag ah = *(const bfrag*)&sAh[ao];
                #pragma unroll
                for (int j = 0; j < 4; ++j)
                    acc[i][j] = __builtin_amdgcn_mfma_f32_16x16x32_bf16(ah, bh[j], acc[i][j], 0, 0, 0);
            }
        }
    }

    // C/D layout: col = lane&15 (fm), row = fq*4 + reg
    #pragma unroll
    for (int i = 0; i < 4; ++i) {
        const int rowb = m0 + wm * 64 + i * 16 + fq * 4;
        #pragma unroll
        for (int j = 0; j < 4; ++j) {
            const int col = n0 + wn * 64 + j * 16 + fm;
            #pragma unroll
            for (int r = 0; r < 4; ++r)
                C[(size_t)(rowb + r) * DIM + col] = acc[i][j][r];
        }
    }
}

// ---------------------------------------------------------------- prep
__device__ __forceinline__ ushort f2bf_bits(float f) {
    __bf16 h = (__bf16)f;                        // RNE
    return __builtin_bit_cast(unsigned short, h);
}
__device__ __forceinline__ float bfbits2f(ushort u) {
    __bf16 h = __builtin_bit_cast(__bf16, u);
    return (float)h;
}

union U16x8 { ushort u[8]; uint4 v; };

__global__ __launch_bounds__(256) void split2(const float* __restrict__ src,
                                              ushort* __restrict__ hi,
                                              ushort* __restrict__ lo)
{
    const size_t i0 = ((size_t)blockIdx.x * 256 + threadIdx.x) * 8;
    const float4 v0 = *(const float4*)(src + i0);
    const float4 v1 = *(const float4*)(src + i0 + 4);
    const float f[8] = {v0.x, v0.y, v0.z, v0.w, v1.x, v1.y, v1.z, v1.w};
    U16x8 h, l;
    #pragma unroll
    for (int j = 0; j < 8; ++j) {
        const ushort hb = f2bf_bits(f[j]);
        h.u[j] = hb;
        l.u[j] = f2bf_bits(f[j] - bfbits2f(hb));
    }
    *(uint4*)(hi + i0) = h.v;
    *(uint4*)(lo + i0) = l.v;
}

__global__ __launch_bounds__(256) void tobf16(const float* __restrict__ src,
                                              ushort* __restrict__ dst)
{
    const size_t i0 = ((size_t)blockIdx.x * 256 + threadIdx.x) * 8;
    const float4 v0 = *(const float4*)(src + i0);
    const float4 v1 = *(const float4*)(src + i0 + 4);
    const float f[8] = {v0.x, v0.y, v0.z, v0.w, v1.x, v1.y, v1.z, v1.w};
    U16x8 h;
    #pragma unroll
    for (int j = 0; j < 8; ++j) h.u[j] = f2bf_bits(f[j]);
    *(uint4*)(dst + i0) = h.v;
}

// ---------------------------------------------------------------- epilogue (proven)
__global__ __launch_bounds__(256) void ladder_epilogue(
    const float* __restrict__ X,
    const float* __restrict__ G,    // gate logits fp32
    const float* __restrict__ Lw,   // (3,6,2048)
    const float* __restrict__ Vw,   // (2048,3)
    float* __restrict__ Out)
{
    const int r = blockIdx.x;
    const int tid = threadIdx.x;
    const int d0 = tid * 8;
    const float* xrow = X + (size_t)r * DIM;
    const float* grow = G + (size_t)r * DIM;

    const float4 xv0 = *(const float4*)(xrow + d0);
    const float4 xv1 = *(const float4*)(xrow + d0 + 4);
    const float4 gv0 = *(const float4*)(grow + d0);
    const float4 gv1 = *(const float4*)(grow + d0 + 4);

    float gated[8];
    {
        const float gx[8] = {gv0.x, gv0.y, gv0.z, gv0.w, gv1.x, gv1.y, gv1.z, gv1.w};
        const float xx[8] = {xv0.x, xv0.y, xv0.z, xv0.w, xv1.x, xv1.y, xv1.z, xv1.w};
        #pragma unroll
        for (int j = 0; j < 8; ++j) {
            const float s = 1.0f / (1.0f + __expf(-gx[j]));
            gated[j] = s * xx[j];
        }
    }

    float part[NL * (DEPTH + 1)];
    #pragma unroll
    for (int lk = 0; lk < NL * (DEPTH + 1); ++lk) {
        const float* lrow = Lw + (size_t)lk * DIM + d0;
        const float4 w0 = *(const float4*)lrow;
        const float4 w1 = *(const float4*)(lrow + 4);
        part[lk] = gated[0] * w0.x + gated[1] * w0.y + gated[2] * w0.z + gated[3] * w0.w
                 + gated[4] * w1.x + gated[5] * w1.y + gated[6] * w1.z + gated[7] * w1.w;
    }

    #pragma unroll
    for (int off = 32; off > 0; off >>= 1) {
        #pragma unroll
        for (int lk = 0; lk < NL * (DEPTH + 1); ++lk)
            part[lk] += __shfl_down(part[lk], off, 64);
    }

    __shared__ float red[4][NL * (DEPTH + 1)];
    __shared__ float zsh[NL];
    const int wave = tid >> 6;
    const int lane = tid & 63;
    if (lane == 0) {
        #pragma unroll
        for (int lk = 0; lk < NL * (DEPTH + 1); ++lk) red[wave][lk] = part[lk];
    }
    __syncthreads();
    if (tid < NL) {
        float a[DEPTH + 1];
        #pragma unroll
        for (int k = 0; k < DEPTH + 1; ++k)
            a[k] = red[0][tid * 6 + k] + red[1][tid * 6 + k]
                 + red[2][tid * 6 + k] + red[3][tid * 6 + k];
        float f = 0.f;
        #pragma unroll
        for (int k = DEPTH - 1; k >= 0; --k) {
            float denom = 1.f + f;
            if (fabsf(denom) < CF_EPS) denom = (denom >= 0.f) ? CF_EPS : -CF_EPS;
            f = a[k + 1] / denom;
        }
        zsh[tid] = a[0] + f;
    }
    __syncthreads();
    const float z0 = zsh[0], z1 = zsh[1], z2 = zsh[2];

    float* orow = Out + (size_t)r * DIM + d0;
    const float4 o0 = *(const float4*)orow;
    const float4 o1 = *(const float4*)(orow + 4);
    float ov[8] = {o0.x, o0.y, o0.z, o0.w, o1.x, o1.y, o1.z, o1.w};
    #pragma unroll
    for (int j = 0; j < 8; ++j) {
        const float* vp = Vw + (size_t)(d0 + j) * NL;
        ov[j] += z0 * vp[0] + z1 * vp[1] + z2 * vp[2];
    }
    *(float4*)orow       = make_float4(ov[0], ov[1], ov[2], ov[3]);
    *(float4*)(orow + 4) = make_float4(ov[4], ov[5], ov[6], ov[7]);
}

// ---------------------------------------------------------------- launch
extern "C" void kernel_launch(void* const* d_in, const int* in_sizes, int n_in,
                              void* d_out, int out_size, void* d_ws, size_t ws_size,
                              hipStream_t stream) {
    const float* X  = (const float*)d_in[0];
    const float* Uw = (const float*)d_in[1];
    const float* Gw = (const float*)d_in[2];
    const float* Lw = (const float*)d_in[3];
    const float* Vw = (const float*)d_in[4];
    float* out = (float*)d_out;

    // ws layout (bytes):
    //   gbuf fp32  @ 0           67108864   (gate logits)
    //   Xh bf16    @ 67108864    33554432
    //   Xl bf16    @ 100663296   33554432
    //   Gwh bf16   @ 134217728    8388608
    //   Gwl bf16   @ 142606336    8388608
    //   Uwh bf16   @ 150994944    8388608
    char* ws = (char*)d_ws;
    float*  gbuf = (float*)ws;
    ushort* Xh  = (ushort*)(ws + 67108864);
    ushort* Xl  = (ushort*)(ws + 100663296);
    ushort* Gwh = (ushort*)(ws + 134217728);
    ushort* Gwl = (ushort*)(ws + 142606336);
    ushort* Uwh = (ushort*)(ws + 150994944);

    split2<<<dim3(8192), dim3(256), 0, stream>>>(X, Xh, Xl);
    split2<<<dim3(2048), dim3(256), 0, stream>>>(Gw, Gwh, Gwl);
    tobf16<<<dim3(2048), dim3(256), 0, stream>>>(Uw, Uwh);

    // merged: bx in [0,32) = (n-tile, gate/u); by = m-tile
    dim3 grid(2 * DIM / 128, NROWS / 128);   // (32, 64)
    dual_gemm<<<grid, dim3(256), 0, stream>>>(Xh, Xl, Gwh, Gwl, Uwh, out, gbuf);

    ladder_epilogue<<<dim3(NROWS), dim3(256), 0, stream>>>(X, gbuf, Lw, Vw, out);
}